// Round 3
// baseline (161.635 us; speedup 1.0000x reference)
//
#include <hip/hip_runtime.h>
#include <hip/hip_cooperative_groups.h>

namespace cg = cooperative_groups;

#define H 48
#define W 64
#define C 256
#define NK 21            // 21 displacements per axis
#define HW (H * W)       // 3072
#define ROWB (W * C)     // ushort elements per channels-last row slice = 16384 (32KB)
#define NJOBS (H * NK)   // 1008 (y, oy) jobs
#define NBLK 504         // 2 jobs/block; 504 blocks x 64KB LDS = 2/CU co-resident

typedef __attribute__((ext_vector_type(8))) short bf16x8;
typedef __attribute__((ext_vector_type(8))) unsigned short u16x8;
typedef __attribute__((ext_vector_type(4))) float f32x4;

__device__ __forceinline__ unsigned short f2bf(float f) {
  unsigned u = __builtin_bit_cast(unsigned, f);
  u = (u + 0x7FFFu + ((u >> 16) & 1u)) >> 16;  // RNE truncate to bf16
  return (unsigned short)u;
}

// issue one 16B global->LDS DMA (wave-uniform LDS base + lane*16)
__device__ __forceinline__ void load16_to_lds(const void* g, void* l) {
  __builtin_amdgcn_global_load_lds(
      (__attribute__((address_space(1))) void*)(unsigned long long)g,
      (__attribute__((address_space(3))) void*)(unsigned int)(unsigned long long)l,
      16, 0, 0);
}

// ---- one (y, oyi) correlation job: 64x64x256 bf16 GEMM + diagonal extraction.
// Byte-identical logic to round-2's corr_mfma body.
__device__ __forceinline__ void corr_job(int job, const unsigned short* __restrict__ f1t,
                                         const unsigned short* __restrict__ f2t,
                                         float* __restrict__ out, char* smem, int tid) {
  const int y = job / NK, oyi = job % NK;
  const int r = y + 2 * oyi - 20;
  float* outBase = out + (size_t)(oyi * NK) * HW + y * W;  // + oxi*HW + x

  if ((unsigned)r >= (unsigned)H) {  // whole oy-band out of range -> zeros
    for (int i = tid; i < NK * W; i += 256) {
      int oxi = i >> 6, x = i & 63;
      outBase[(size_t)oxi * HW + x] = 0.f;
    }
    return;  // uniform across block; no barriers on this path
  }

  const int wave = tid >> 6, lane = tid & 63;

  __syncthreads();  // prior users of smem (transpose tile / previous job) done

  // ---- stage A (f1t row y) and B (f2t row r): 32KB each, pre-swizzled source
  {
    const char* gA = (const char*)(f1t + (size_t)y * ROWB);
    const char* gB = (const char*)(f2t + (size_t)r * ROWB);
#pragma unroll
    for (int it = 0; it < 8; ++it) {
      int slot = ((it * 4 + wave) << 10) + (lane << 4);
      int src_off = slot ^ (((slot >> 9) & 7) << 4);
      load16_to_lds(gA + src_off, smem + slot);
      load16_to_lds(gB + src_off, smem + 32768 + slot);
    }
  }
  __syncthreads();

  // ---- 64x64x256 Gram via mfma_f32_16x16x32_bf16; wave w owns rows [16w,16w+16)
  f32x4 acc[4] = {};
  const int sw = (lane & 7) << 4;
  const int abase = ((wave * 16 + (lane & 15)) << 9) + ((lane >> 4) << 4);
#pragma unroll
  for (int ks = 0; ks < 8; ++ks) {
    bf16x8 a = *reinterpret_cast<const bf16x8*>(smem + ((abase + (ks << 6)) ^ sw));
#pragma unroll
    for (int tn = 0; tn < 4; ++tn) {
      int baddr = ((((tn * 16 + (lane & 15)) << 9) + (ks << 6) + ((lane >> 4) << 4)) ^ sw);
      bf16x8 bb = *reinterpret_cast<const bf16x8*>(smem + 32768 + baddr);
      acc[tn] = __builtin_amdgcn_mfma_f32_16x16x32_bf16(a, bb, acc[tn], 0, 0, 0);
    }
  }
  __syncthreads();  // all reads of A-region done before overlaying with M

  // ---- write M to LDS; C/D layout: col=lane&15, row=(lane>>4)*4+reg (m89)
  float* M = (float*)smem;  // [64][66]
#pragma unroll
  for (int tn = 0; tn < 4; ++tn) {
#pragma unroll
    for (int j = 0; j < 4; ++j) {
      int x1 = (wave << 4) + ((lane >> 4) << 2) + j;
      int x2 = (tn << 4) + (lane & 15);
      M[x1 * 66 + x2] = acc[tn][j];
    }
  }
  __syncthreads();

  // ---- band extraction: out[(oyi*21+oxi), y, x] = M[x][x + 2*oxi - 20]
  for (int i = tid; i < NK * W; i += 256) {
    int oxi = i >> 6, x = i & 63;
    int x2 = x + 2 * oxi - 20;
    float v = ((unsigned)x2 < (unsigned)W) ? M[x * 66 + x2] : 0.f;
    outBase[(size_t)oxi * HW + x] = v;
  }
}

// ---- fused cooperative kernel: transpose tiles -> grid.sync -> 2 corr jobs/block
#define TP_HW 256
#define TP_C 16
__global__ __launch_bounds__(256, 2) void fused_corr(
    const float* __restrict__ f1, const float* __restrict__ f2,
    unsigned short* __restrict__ f1t, unsigned short* __restrict__ f2t,
    float* __restrict__ out) {
  __shared__ char smem[65536];
  const int t = threadIdx.x;
  const int b = blockIdx.x;

  // phase 1: 384 transpose tile-jobs (tile = 16c x 256hw), identical to round-2
  if (b < 384) {
    const int tensor = b >= 192;
    const int jj = b - tensor * 192;
    const int hw0 = (jj % 12) * TP_HW;
    const int c0 = (jj / 12) * TP_C;
    const float* src = tensor ? f2 : f1;
    unsigned short* dst = tensor ? f2t : f1t;
    unsigned short(*tile)[TP_HW + 4] = (unsigned short(*)[TP_HW + 4])smem;

    const int lane_hw = (t & 63) * 4;
    const int crow = t >> 6;
#pragma unroll
    for (int i = 0; i < 4; ++i) {
      int c_local = i * 4 + crow;
      const float* p = src + (size_t)(c0 + c_local) * HW + hw0 + lane_hw;
      float4 v = *reinterpret_cast<const float4*>(p);
      ushort4 bq;
      bq.x = f2bf(v.x); bq.y = f2bf(v.y); bq.z = f2bf(v.z); bq.w = f2bf(v.w);
      *reinterpret_cast<ushort4*>(&tile[c_local][lane_hw]) = bq;
    }
    __syncthreads();
    unsigned short vals[16];
#pragma unroll
    for (int j = 0; j < 16; ++j) vals[j] = tile[j][t];
    unsigned short* o = dst + (size_t)(hw0 + t) * C + c0;
    *reinterpret_cast<u16x8*>(o) = *reinterpret_cast<const u16x8*>(&vals[0]);
    *reinterpret_cast<u16x8*>(o + 8) = *reinterpret_cast<const u16x8*>(&vals[8]);
  }

  __threadfence();        // make ws writes device-visible (belt & braces)
  cg::this_grid().sync(); // all transposes complete + visible

  corr_job(b, f1t, f2t, out, smem, t);
  corr_job(b + NBLK, f1t, f2t, out, smem, t);
}

// Fallback if d_ws is too small: direct fp32, coalesced along x.
__global__ __launch_bounds__(256) void corr_direct(
    const float* __restrict__ f1, const float* __restrict__ f2, float* __restrict__ out) {
  int idx = blockIdx.x * 256 + threadIdx.x;
  if (idx >= 441 * HW) return;
  int x = idx & 63;
  int y = (idx >> 6) % H;
  int o = idx / HW;
  int oyi = o / NK, oxi = o % NK;
  int ry = y + 2 * oyi - 20, rx = x + 2 * oxi - 20;
  float acc = 0.f;
  if ((unsigned)ry < (unsigned)H && (unsigned)rx < (unsigned)W) {
    const float* p1 = f1 + y * W + x;
    const float* p2 = f2 + ry * W + rx;
#pragma unroll 8
    for (int c = 0; c < C; ++c) acc += p1[c * HW] * p2[c * HW];
  }
  out[idx] = acc;
}

extern "C" void kernel_launch(void* const* d_in, const int* in_sizes, int n_in,
                              void* d_out, int out_size, void* d_ws, size_t ws_size,
                              hipStream_t stream) {
  const float* f1 = (const float*)d_in[0];
  const float* f2 = (const float*)d_in[1];
  float* out = (float*)d_out;

  const size_t needed = 2ull * HW * C * sizeof(unsigned short);  // ~3.1 MB
  if (ws_size >= needed) {
    unsigned short* f1t = (unsigned short*)d_ws;
    unsigned short* f2t = f1t + (size_t)HW * C;
    void* args[] = {(void*)&f1, (void*)&f2, (void*)&f1t, (void*)&f2t, (void*)&out};
    hipLaunchCooperativeKernel((const void*)fused_corr, dim3(NBLK), dim3(256), args, 0,
                               stream);
  } else {
    int n = 441 * HW;
    corr_direct<<<(n + 255) / 256, 256, 0, stream>>>(f1, f2, out);
  }
}

// Round 4
// 18.891 us; speedup vs baseline: 8.5561x; 8.5561x over previous
//
#include <hip/hip_runtime.h>

#define H 48
#define W 64
#define C 256
#define NK 21               // 21 displacements per axis
#define HW (H * W)          // 3072
#define LDS_STRIDE 528      // 256 bf16 = 512B + 16B pad (keeps 16B alignment, kills bank conflicts)
#define LDS_TENSOR (64 * LDS_STRIDE)  // 33792 B per staged row-slice

typedef __attribute__((ext_vector_type(8))) short bf16x8;
typedef __attribute__((ext_vector_type(4))) float f32x4;

// pack two fp32 -> two bf16 (RNE) in one u32: lo = bf(a), hi = bf(b)
__device__ __forceinline__ unsigned pack2bf(float a, float b) {
  unsigned ua = __builtin_bit_cast(unsigned, a);
  unsigned ub = __builtin_bit_cast(unsigned, b);
  ua = (ua + 0x7FFFu + ((ua >> 16) & 1u)) >> 16;
  ub = (ub + 0x7FFFu + ((ub >> 16) & 1u)) & 0xFFFF0000u;
  return ua | ub;
}

// Stage one row-slice src[c][x] (c=0..255, x=0..63; element src[c*HW + x]) into
// LDS as bf16 [x][c] with row stride LDS_STRIDE.
// Per pass: 8 coalesced 256B scalar loads (lane = x), pack, one ds_write_b128.
// Write banks: within a 16-lane phase rows x=0..15 -> bank start 4x mod 32 = 2-way (free).
__device__ __forceinline__ void stage_row(const float* __restrict__ src, char* lds, int tid) {
  const int lane = tid & 63, wave = tid >> 6;
  const float* col = src + lane;  // x = lane
#pragma unroll
  for (int i = 0; i < 8; ++i) {
    const int oct = i * 4 + wave;  // c-octet 0..31
    const float* p = col + (size_t)oct * 8 * HW;
    float v0 = p[0], v1 = p[HW], v2 = p[2 * HW], v3 = p[3 * HW];
    float v4 = p[4 * HW], v5 = p[5 * HW], v6 = p[6 * HW], v7 = p[7 * HW];
    uint4 w;
    w.x = pack2bf(v0, v1);
    w.y = pack2bf(v2, v3);
    w.z = pack2bf(v4, v5);
    w.w = pack2bf(v6, v7);
    *reinterpret_cast<uint4*>(lds + lane * LDS_STRIDE + oct * 16) = w;
  }
}

// One block per (y, oyi) job. Phase 0: stage f1 row y and f2 row r (on-the-fly
// fp32->bf16 transpose). Phase 1: 64x64x256 Gram via mfma_f32_16x16x32_bf16.
// Phase 2: extract the 21 stride-2 diagonals.
__global__ __launch_bounds__(256, 2) void corr_fused(
    const float* __restrict__ f1, const float* __restrict__ f2, float* __restrict__ out) {
  __shared__ char smem[2 * LDS_TENSOR];  // 67584 B -> 2 blocks/CU
  const int b = blockIdx.x;
  const int y = b / NK, oyi = b % NK;
  const int r = y + 2 * oyi - 20;
  const int tid = threadIdx.x;
  float* outBase = out + (size_t)(oyi * NK) * HW + y * W;  // + oxi*HW + x

  if ((unsigned)r >= (unsigned)H) {  // whole oy-band out of range -> zeros
    for (int i = tid; i < NK * W; i += 256) {
      int oxi = i >> 6, x = i & 63;
      outBase[(size_t)oxi * HW + x] = 0.f;
    }
    return;
  }

  stage_row(f1 + (size_t)y * W, smem, tid);
  stage_row(f2 + (size_t)r * W, smem + LDS_TENSOR, tid);
  __syncthreads();

  // ---- 64x64x256 Gram; wave w owns output rows [16w, 16w+16)
  const int wave = tid >> 6, lane = tid & 63;
  f32x4 acc[4] = {};
  const int koff = (lane >> 4) * 16;                      // k-byte offset within 32-k group
  const char* aRow = smem + (wave * 16 + (lane & 15)) * LDS_STRIDE + koff;
  const char* bBase = smem + LDS_TENSOR + (lane & 15) * LDS_STRIDE + koff;
#pragma unroll
  for (int ks = 0; ks < 8; ++ks) {
    bf16x8 a = *reinterpret_cast<const bf16x8*>(aRow + ks * 64);
#pragma unroll
    for (int tn = 0; tn < 4; ++tn) {
      bf16x8 bb = *reinterpret_cast<const bf16x8*>(bBase + tn * 16 * LDS_STRIDE + ks * 64);
      acc[tn] = __builtin_amdgcn_mfma_f32_16x16x32_bf16(a, bb, acc[tn], 0, 0, 0);
    }
  }
  __syncthreads();  // all fragment reads done before overlaying M

  // ---- write M to LDS; C/D layout: col=lane&15, row=(lane>>4)*4+reg (m89)
  float* M = (float*)smem;  // [64][66]
#pragma unroll
  for (int tn = 0; tn < 4; ++tn) {
#pragma unroll
    for (int j = 0; j < 4; ++j) {
      int x1 = (wave << 4) + ((lane >> 4) << 2) + j;
      int x2 = (tn << 4) + (lane & 15);
      M[x1 * 66 + x2] = acc[tn][j];
    }
  }
  __syncthreads();

  // ---- band extraction: out[(oyi*21+oxi), y, x] = M[x][x + 2*oxi - 20]
  for (int i = tid; i < NK * W; i += 256) {
    int oxi = i >> 6, x = i & 63;
    int x2 = x + 2 * oxi - 20;
    float v = ((unsigned)x2 < (unsigned)W) ? M[x * 66 + x2] : 0.f;
    outBase[(size_t)oxi * HW + x] = v;
  }
}

extern "C" void kernel_launch(void* const* d_in, const int* in_sizes, int n_in,
                              void* d_out, int out_size, void* d_ws, size_t ws_size,
                              hipStream_t stream) {
  (void)in_sizes; (void)n_in; (void)d_ws; (void)ws_size; (void)out_size;
  const float* f1 = (const float*)d_in[0];
  const float* f2 = (const float*)d_in[1];
  float* out = (float*)d_out;
  corr_fused<<<H * NK, 256, 0, stream>>>(f1, f2, out);
}